// Round 1
// baseline (4410.500 us; speedup 1.0000x reference)
//
#include <hip/hip_runtime.h>
#include <stdint.h>

// ActuatorPolicyNet: x[2048,512] -> LSTM(H=1024) -> fc1 -> fc2 -> mean head.
// Phase A: gx GEMM. Phase B: persistent-resident LSTM recurrence with
// register-held w_hh and sentinel-polled cross-CU h exchange. Phase C: fc GEMMs + head.

#define T_SEQ 2048
#define H 1024
#define G4 4096
#define K_IN 512
#define SENT 0x7FC0DEADu  // NaN bit pattern; real h values are never NaN

__device__ __forceinline__ float sigmoidf_(float x) { return 1.0f / (1.0f + __expf(-x)); }
__device__ __forceinline__ float tanhf_(float x) { return 1.0f - 2.0f / (1.0f + __expf(2.0f * x)); }

// ---------------- init: h_hist[0] = h0, rows 1..2048 = sentinel ----------------
__global__ void init_k(const float* __restrict__ h0, float* __restrict__ h_hist) {
  int idx = blockIdx.x * blockDim.x + threadIdx.x;
  if (idx < H) {
    h_hist[idx] = h0[idx];
  } else if (idx < (T_SEQ + 1) * H) {
    ((unsigned*)h_hist)[idx] = SENT;
  }
}

// ---------------- generic fp32 GEMM: C = act(A[M,K] @ Bw[N,K]^T + b1 (+ b2)) ----------------
#define BM 64
#define BN 64
#define BK 32
#define LDT 68  // padded LDS stride (keeps float4 alignment, 2-way max bank aliasing)

template <bool RELU, bool HASB2>
__global__ __launch_bounds__(256) void gemm_bias_k(
    const float* __restrict__ A, const float* __restrict__ Bw,
    const float* __restrict__ b1, const float* __restrict__ b2,
    float* __restrict__ C, int M, int N, int K) {
  __shared__ float As[BK][LDT];
  __shared__ float Bs[BK][LDT];
  const int tid = threadIdx.x;
  const int m0 = blockIdx.y * BM;
  const int n0 = blockIdx.x * BN;
  const int tx = tid & 15, ty = tid >> 4;  // 16x16 threads, 4x4 microtile
  const int srow = tid >> 2;               // 0..63 staging row
  const int skq = tid & 3;                 // 0..3  staging k-quarter

  float acc[4][4];
#pragma unroll
  for (int i = 0; i < 4; i++)
#pragma unroll
    for (int j = 0; j < 4; j++) acc[i][j] = 0.f;

  const float* Arow = A + (size_t)(m0 + srow) * K;
  const float* Brow = Bw + (size_t)(n0 + srow) * K;

  for (int k0 = 0; k0 < K; k0 += BK) {
    float4 a0 = *(const float4*)(Arow + k0 + skq * 8);
    float4 a1 = *(const float4*)(Arow + k0 + skq * 8 + 4);
    float4 c0_ = *(const float4*)(Brow + k0 + skq * 8);
    float4 c1_ = *(const float4*)(Brow + k0 + skq * 8 + 4);
    __syncthreads();  // previous tile fully consumed
    const int kb = skq * 8;
    As[kb + 0][srow] = a0.x; As[kb + 1][srow] = a0.y; As[kb + 2][srow] = a0.z; As[kb + 3][srow] = a0.w;
    As[kb + 4][srow] = a1.x; As[kb + 5][srow] = a1.y; As[kb + 6][srow] = a1.z; As[kb + 7][srow] = a1.w;
    Bs[kb + 0][srow] = c0_.x; Bs[kb + 1][srow] = c0_.y; Bs[kb + 2][srow] = c0_.z; Bs[kb + 3][srow] = c0_.w;
    Bs[kb + 4][srow] = c1_.x; Bs[kb + 5][srow] = c1_.y; Bs[kb + 6][srow] = c1_.z; Bs[kb + 7][srow] = c1_.w;
    __syncthreads();
#pragma unroll
    for (int kk = 0; kk < BK; kk++) {
      float av[4], bv[4];
      *(float4*)av = *(const float4*)&As[kk][ty * 4];
      *(float4*)bv = *(const float4*)&Bs[kk][tx * 4];
#pragma unroll
      for (int i = 0; i < 4; i++)
#pragma unroll
        for (int j = 0; j < 4; j++) acc[i][j] = fmaf(av[i], bv[j], acc[i][j]);
    }
  }

  float bb[4];
#pragma unroll
  for (int j = 0; j < 4; j++) {
    bb[j] = b1[n0 + tx * 4 + j];
    if (HASB2) bb[j] += b2[n0 + tx * 4 + j];
  }
#pragma unroll
  for (int i = 0; i < 4; i++) {
    float4 o;
    float* op = (float*)&o;
#pragma unroll
    for (int j = 0; j < 4; j++) {
      float v = acc[i][j] + bb[j];
      op[j] = RELU ? fmaxf(v, 0.f) : v;
    }
    *(float4*)&C[(size_t)(m0 + ty * 4 + i) * N + n0 + tx * 4] = o;
  }
}

// ---------------- persistent LSTM recurrence ----------------
// 128 wgs x 512 thr, all co-resident (<=256 CUs). wg owns 8 hidden units
// (32 gate rows). Thread (row=lane&31, seg=wave*2+(lane>>5)) holds
// w_hh[grow][seg*64..+64) in 64 VGPRs. h(t) exchanged via h_hist with
// NaN-sentinel data polling (device-scope relaxed atomics).
#define NWG 128
#define NTHR 512

__global__ __launch_bounds__(NTHR, 2) void lstm_k(
    const float* __restrict__ gx, const float* __restrict__ w_hh,
    const float* __restrict__ c0, float* __restrict__ h_hist,
    float* __restrict__ out) {
  unsigned* h_u = (unsigned*)h_hist;
  __shared__ float hbuf[H];
  __shared__ float partial[8][32];
  const int tid = threadIdx.x;
  const int wg = blockIdx.x;
  const int wave = tid >> 6, lane = tid & 63;
  const int row = lane & 31;                 // 0..31 gate-row within wg
  const int seg = wave * 2 + (lane >> 5);    // 0..15 k-segment
  const int g = row >> 3, u = row & 7;
  const int grow = g * 1024 + wg * 8 + u;    // global gate row

  // preload weights into registers
  float4 wreg[16];
  {
    const float* wp = w_hh + (size_t)grow * H + seg * 64;
#pragma unroll
    for (int j = 0; j < 16; j++) wreg[j] = *(const float4*)(wp + j * 4);
  }
  float c = 0.f;
  if (wave == 0 && lane < 8) c = c0[wg * 8 + lane];

  const int i0 = tid * 2;
  for (int t = 0; t < T_SEQ; t++) {
    // prefetch this step's gx early so its latency overlaps the poll
    float gxv = 0.f;
    if (wave == 0) gxv = gx[(size_t)t * G4 + grow];

    // stage h(t): poll until non-sentinel, then LDS
    {
      unsigned* src = h_u + (size_t)t * H;
      unsigned a, b;
      do {
        a = __hip_atomic_load(&src[i0], __ATOMIC_RELAXED, __HIP_MEMORY_SCOPE_AGENT);
      } while (a == SENT);
      do {
        b = __hip_atomic_load(&src[i0 + 1], __ATOMIC_RELAXED, __HIP_MEMORY_SCOPE_AGENT);
      } while (b == SENT);
      hbuf[i0] = __uint_as_float(a);
      hbuf[i0 + 1] = __uint_as_float(b);
    }
    __syncthreads();

    // partial dot: 64 MACs per thread, h via wave-uniform LDS broadcast
    float accv = 0.f;
    const float* hs = &hbuf[seg * 64];
#pragma unroll
    for (int j = 0; j < 16; j++) {
      float4 hv = *(const float4*)(hs + j * 4);
      float4 w = wreg[j];
      accv = fmaf(w.x, hv.x, accv);
      accv = fmaf(w.y, hv.y, accv);
      accv = fmaf(w.z, hv.z, accv);
      accv = fmaf(w.w, hv.w, accv);
    }
    accv += __shfl_down(accv, 32);  // combine the wave's two segments
    if (lane < 32) partial[wave][lane] = accv;
    __syncthreads();

    if (wave == 0) {
      const int wsel = lane >> 5;  // lanes 0-31 sum waves 0-3, 32-63 sum 4-7
      float s = partial[wsel * 4 + 0][row] + partial[wsel * 4 + 1][row] +
                partial[wsel * 4 + 2][row] + partial[wsel * 4 + 3][row];
      s += __shfl_down(s, 32);  // lanes 0..31 now hold full row sums
      float pre = s + gxv;
      float act = (g == 2) ? tanhf_(pre) : sigmoidf_(pre);
      float iv = __shfl(act, u);
      float fv = __shfl(act, 8 + u);
      float gv = __shfl(act, 16 + u);
      float ov = __shfl(act, 24 + u);
      if (lane < 8) {
        c = fmaf(fv, c, iv * gv);
        float hn = ov * tanhf_(c);
        __hip_atomic_store(&h_u[(size_t)(t + 1) * H + wg * 8 + lane],
                           __float_as_uint(hn), __ATOMIC_RELAXED,
                           __HIP_MEMORY_SCOPE_AGENT);
        if (t == T_SEQ - 1) {
          out[16384 + wg * 8 + lane] = hn;  // hT
          out[17408 + wg * 8 + lane] = c;   // cT
        }
      }
    }
  }
}

// ---------------- head: action_mean + log_std broadcast ----------------
__global__ __launch_bounds__(256) void head_k(
    const float* __restrict__ h2, const float* __restrict__ mean_w,
    const float* __restrict__ mean_b, const float* __restrict__ log_std,
    float* __restrict__ out) {
  const int t = blockIdx.x;
  const int tid = threadIdx.x;
  const int wave = tid >> 6, lane = tid & 63;  // wave = output index (OUT=4)
  const float* hr = h2 + (size_t)t * H;
  const float* wr = mean_w + (size_t)wave * H;
  float s = 0.f;
#pragma unroll
  for (int j = 0; j < 16; j++) s = fmaf(hr[lane + j * 64], wr[lane + j * 64], s);
#pragma unroll
  for (int off = 32; off > 0; off >>= 1) s += __shfl_down(s, off);
  if (lane == 0) out[t * 4 + wave] = s + mean_b[wave];
  if (tid < 4) out[8192 + t * 4 + tid] = log_std[tid];
}

extern "C" void kernel_launch(void* const* d_in, const int* in_sizes, int n_in,
                              void* d_out, int out_size, void* d_ws, size_t ws_size,
                              hipStream_t stream) {
  const float* x      = (const float*)d_in[0];
  const float* h0     = (const float*)d_in[1];
  const float* c0     = (const float*)d_in[2];
  const float* w_ih   = (const float*)d_in[3];
  const float* w_hh   = (const float*)d_in[4];
  const float* b_ih   = (const float*)d_in[5];
  const float* b_hh   = (const float*)d_in[6];
  const float* fc1_w  = (const float*)d_in[7];
  const float* fc1_b  = (const float*)d_in[8];
  const float* fc2_w  = (const float*)d_in[9];
  const float* fc2_b  = (const float*)d_in[10];
  const float* mean_w = (const float*)d_in[11];
  const float* mean_b = (const float*)d_in[12];
  const float* lstd   = (const float*)d_in[13];
  float* out = (float*)d_out;

  // workspace layout (peak ~40.4 MB):
  //   gx:     [0, 32 MB)              2048*4096 fp32  (reused as h1/h2 after LSTM)
  //   h_hist: [32 MB, 40.4 MB)        2049*1024 fp32  (row 0 = h0, rows 1..2048 = ys, row 2048 tail = hT)
  float* gx = (float*)d_ws;
  float* h_hist = gx + (size_t)T_SEQ * G4;
  float* h1 = gx;
  float* h2 = gx + (size_t)T_SEQ * H;

  init_k<<<dim3((T_SEQ + 1) * H / 256), 256, 0, stream>>>(h0, h_hist);
  gemm_bias_k<false, true><<<dim3(G4 / BN, T_SEQ / BM), 256, 0, stream>>>(
      x, w_ih, b_ih, b_hh, gx, T_SEQ, G4, K_IN);
  lstm_k<<<dim3(NWG), NTHR, 0, stream>>>(gx, w_hh, c0, h_hist, out);
  gemm_bias_k<true, false><<<dim3(H / BN, T_SEQ / BM), 256, 0, stream>>>(
      h_hist + H, fc1_w, fc1_b, nullptr, h1, T_SEQ, H, H);
  gemm_bias_k<true, false><<<dim3(H / BN, T_SEQ / BM), 256, 0, stream>>>(
      h1, fc2_w, fc2_b, nullptr, h2, T_SEQ, H, H);
  head_k<<<dim3(T_SEQ), 256, 0, stream>>>(h2, mean_w, mean_b, lstd, out);
}